// Round 15
// baseline (3019.838 us; speedup 1.0000x reference)
//
#include <hip/hip_runtime.h>

#define M_DIM 8192
#define K_DIM 4096
#define N_DIM 16384
#define KT 32   // K tiles of 128 (= one weight scale block)

typedef __attribute__((ext_vector_type(4))) int i32x4;
typedef __attribute__((ext_vector_type(4))) float f32x4;

__device__ __forceinline__ int pack4(int a, int b, int c, int d) {
  return (a & 255) | ((b & 255) << 8) | ((c & 255) << 16) | (d << 24);
}

// ---- pre-pass 1: x fp32 -> int8 per-row, sx[row] = rowmax/127 ------------
__global__ __launch_bounds__(256) void quant_x_kernel(const float* __restrict__ x,
    char* __restrict__ xq, float* __restrict__ sx) {
  const int row = blockIdx.x;
  const int tid = threadIdx.x;
  const float4* xr = reinterpret_cast<const float4*>(x + (size_t)row * K_DIM);
  float4 v[4];
  float m = 0.f;
#pragma unroll
  for (int j = 0; j < 4; ++j) {
    v[j] = xr[tid * 4 + j];
    m = fmaxf(m, fmaxf(fmaxf(fabsf(v[j].x), fabsf(v[j].y)),
                       fmaxf(fabsf(v[j].z), fabsf(v[j].w))));
  }
#pragma unroll
  for (int o = 32; o > 0; o >>= 1) m = fmaxf(m, __shfl_xor(m, o));
  __shared__ float wm[4];
  if ((tid & 63) == 0) wm[tid >> 6] = m;
  __syncthreads();
  m = fmaxf(fmaxf(wm[0], wm[1]), fmaxf(wm[2], wm[3]));
  const float r = (m > 0.f) ? 127.f / m : 0.f;
  i32x4 pk;
#pragma unroll
  for (int j = 0; j < 4; ++j)
    pk[j] = pack4((int)rintf(v[j].x * r), (int)rintf(v[j].y * r),
                  (int)rintf(v[j].z * r), (int)rintf(v[j].w * r));
  reinterpret_cast<i32x4*>(xq + (size_t)row * K_DIM)[tid] = pk;
  if (tid == 0) sx[row] = (m > 0.f) ? m / 127.f : 0.f;
}

// ---- pre-pass 2: w_q int32 -> int8 (exact) -------------------------------
__global__ void repack_w_kernel(const int* __restrict__ wq, char* __restrict__ w8, int n16) {
  int i = blockIdx.x * blockDim.x + threadIdx.x;
  const int stride = gridDim.x * blockDim.x;
  const int4* q = reinterpret_cast<const int4*>(wq);
  i32x4* o = reinterpret_cast<i32x4*>(w8);
  for (; i < n16; i += stride) {
    int4 a = q[4 * i], b = q[4 * i + 1], c = q[4 * i + 2], d = q[4 * i + 3];
    i32x4 r;
    r[0] = pack4(a.x, a.y, a.z, a.w);
    r[1] = pack4(b.x, b.y, b.z, b.w);
    r[2] = pack4(c.x, c.y, c.z, c.w);
    r[3] = pack4(d.x, d.y, d.z, d.w);
    o[i] = r;
  }
}

// ---- async global -> LDS, 16 B per lane ----------------------------------
__device__ __forceinline__ void gload16(const void* g, void* l) {
  __builtin_amdgcn_global_load_lds(
      (const __attribute__((address_space(1))) unsigned int*)g,
      (__attribute__((address_space(3))) unsigned int*)l, 16, 0, 0);
}

#define BAR() do { asm volatile("" ::: "memory"); \
                   __builtin_amdgcn_s_barrier();  \
                   asm volatile("" ::: "memory"); } while (0)

#define MFI(a, b, c) __builtin_amdgcn_mfma_i32_16x16x64_i8(a, b, c, 0, 0, 0)

// ---- 128x128x128 8-wave int8 GEMM, A-direct + fa double-bank -------------
// C = sx[row] * (sum_kb ws[nb][kb] * (Aq . Bq^T)_kb) + bias
// B in LDS (dbuf, XOR swizzle, global_load_lds). A read straight from
// global into regs ONE TILE AHEAD (banks faX/faY) so L2 latency hides
// under the previous tile's MFMA burst. vmcnt ledger (issue order per
// tile: fa(t+1) early, B(t+2) stage late): steady state = vmcnt(6) before
// MFMA (drains fa(t)) and vmcnt(6) after stage (drains B(t+1)).
__global__ __launch_bounds__(512, 4) void gemm_kernel(
    const char* __restrict__ Aq, const char* __restrict__ Bq,
    const float* __restrict__ ws, const float* __restrict__ sx,
    const float* __restrict__ bias, float* __restrict__ C) {
  // buf p (16K): B [128][128B] at p*16384. scale row (32 floats) at 32768.
  __shared__ __align__(128) char lds[32768 + 128];

  const int tid = threadIdx.x;
  const int lane = tid & 63, wid = tid >> 6;   // 8 waves
  const int wr = wid >> 1, wc = wid & 1;       // 4x2 wave grid, 32x64/wave

  // Supertile ordering: grid 8192 = 64(tm) x 128(tn) tiles.
  // Super = 16x16 tiles (A 8MB + B 8MB slice, L3-resident).
  const int bid = blockIdx.x;
  const int r = bid & 255;                 // block within super
  const int s = bid >> 8;                  // super id 0..31
  const int sm = s & 3, sn = s >> 2;       // 4 x 8 supers
  const int tm = sm * 16 + (r & 15);       // 0..63
  const int tn = sn * 16 + (r >> 4);       // 0..127

  // stage this block's scale row: ws[tn][0..32)
  if (tid < 32) *(float*)(lds + 32768 + tid * 4) = ws[tn * 32 + tid];

  // ---- B staging: per-lane pre-swizzled global source, linear LDS dest ---
  const int srow = tid >> 3;                         // 0..63
  const int kswz = ((tid & 7) ^ (srow & 7)) << 4;    // swizzled byte offset
  const char* bSrc = Bq + (size_t)(tn * 128 + srow) * K_DIM + kswz;
  const int ldst = wid << 10;                        // wave-uniform

#define STAGE_B(tt, g, b) gload16(bSrc + (size_t)(g)*64*K_DIM + (size_t)(tt)*128, \
                                  lds + (b)*16384 + (g)*8192 + ldst)

  // ---- fb addressing (swizzled): unit u stored at u^(row&7) --------------
  const int hi = lane >> 4, lo3 = lane & 7;
  const int aks0 = ((0 + hi) ^ lo3) << 4;   // kstep 0 (k 0..63)
  const int aks1 = ((4 + hi) ^ lo3) << 4;   // kstep 1 (k 64..127)
  const int boff = (wc * 64 + (lane & 15)) * 128;

  // ---- A-direct addressing: row = lane&15 (+mi*16), k-16B = lane>>4 ------
  const char* aW = Aq + (size_t)(tm * 128 + wr * 32 + (lane & 15)) * K_DIM
                      + ((lane >> 4) << 4);

#define LOAD_FA(FA, tt) do { \
    FA[0][0] = *(const i32x4*)(aW + (size_t)0  * K_DIM + (tt) * 128); \
    FA[0][1] = *(const i32x4*)(aW + (size_t)0  * K_DIM + (tt) * 128 + 64); \
    FA[1][0] = *(const i32x4*)(aW + (size_t)16 * K_DIM + (tt) * 128); \
    FA[1][1] = *(const i32x4*)(aW + (size_t)16 * K_DIM + (tt) * 128 + 64); \
  } while (0)

  i32x4 faX[2][2], faY[2][2];
  f32x4 accf[2][4] = {};

  // ---- prologue: order matters for the vmcnt ledger ----------------------
  STAGE_B(0, 0, 0); STAGE_B(0, 1, 0);   // B(0): 2 loads (oldest)
  LOAD_FA(faX, 0);                      // fa(0): 4 loads
  STAGE_B(1, 0, 1); STAGE_B(1, 1, 1);   // B(1): 2 loads (newest)
  asm volatile("s_waitcnt vmcnt(2) lgkmcnt(0)" ::: "memory");  // B(0)+fa(0)+scales
  BAR();

#define TILE(t, FAc, FAn) do { \
    const int p = (t) & 1; \
    const char* Bb = lds + p * 16384 + boff; \
    const float csc = *(const float*)(lds + 32768 + ((t) << 2)); \
    /* fb: 8 ds_read_b128; fa(t+1) issued behind them */ \
    i32x4 fb[4][2]; \
    _Pragma("unroll") for (int ni = 0; ni < 4; ++ni) { \
      fb[ni][0] = *(const i32x4*)(Bb + ni * 2048 + aks0); \
      fb[ni][1] = *(const i32x4*)(Bb + ni * 2048 + aks1); \
    } \
    if ((t) + 1 < KT) LOAD_FA(FAn, (t) + 1); \
    asm volatile("s_waitcnt lgkmcnt(0)" ::: "memory"); \
    if ((t) + 1 < KT) asm volatile("s_waitcnt vmcnt(6)" ::: "memory"); \
    else              asm volatile("s_waitcnt vmcnt(0)" ::: "memory"); \
    /* 16 MFMA from bank FAc + immediate rescale */ \
    _Pragma("unroll") for (int mi = 0; mi < 2; ++mi) { \
      i32x4 q0, q1, q2, q3; \
      const i32x4 z4 = {0, 0, 0, 0}; \
      __builtin_amdgcn_s_setprio(1); \
      q0 = MFI(FAc[mi][0], fb[0][0], z4); \
      q1 = MFI(FAc[mi][0], fb[1][0], z4); \
      q2 = MFI(FAc[mi][0], fb[2][0], z4); \
      q3 = MFI(FAc[mi][0], fb[3][0], z4); \
      q0 = MFI(FAc[mi][1], fb[0][1], q0); \
      q1 = MFI(FAc[mi][1], fb[1][1], q1); \
      q2 = MFI(FAc[mi][1], fb[2][1], q2); \
      q3 = MFI(FAc[mi][1], fb[3][1], q3); \
      __builtin_amdgcn_s_setprio(0); \
      _Pragma("unroll") for (int e = 0; e < 4; ++e) { \
        accf[mi][0][e] += csc * (float)q0[e]; \
        accf[mi][1][e] += csc * (float)q1[e]; \
        accf[mi][2][e] += csc * (float)q2[e]; \
        accf[mi][3][e] += csc * (float)q3[e]; \
      } \
    } \
    BAR();   /* all waves consumed buf p (fb in regs before MFMA) */ \
    if ((t) + 2 < KT) { \
      STAGE_B((t) + 2, 0, p); STAGE_B((t) + 2, 1, p); \
      asm volatile("s_waitcnt vmcnt(6)" ::: "memory");  /* B(t+1) landed */ \
    } else if ((t) == KT - 2) { \
      asm volatile("s_waitcnt vmcnt(4)" ::: "memory");  /* B(KT-1) landed */ \
    } \
    if ((t) + 1 < KT) BAR(); \
  } while (0)

  for (int tt = 0; tt < KT; tt += 2) {
    TILE(tt, faX, faY);
    TILE(tt + 1, faY, faX);
  }

  // ---- epilogue: C/D layout col=lane&15, row=(lane>>4)*4+reg; NT stores --
  const int crow0 = tm * 128 + wr * 32 + ((lane >> 4) << 2);
  const int ccol0 = tn * 128 + wc * 64 + (lane & 15);
#pragma unroll
  for (int mi = 0; mi < 2; ++mi) {
    float sxv[4];
#pragma unroll
    for (int e = 0; e < 4; ++e) sxv[e] = sx[crow0 + mi * 16 + e];
#pragma unroll
    for (int ni = 0; ni < 4; ++ni) {
      const float bv = bias[ccol0 + ni * 16];
#pragma unroll
      for (int e = 0; e < 4; ++e)
        __builtin_nontemporal_store(
            sxv[e] * accf[mi][ni][e] + bv,
            &C[(size_t)(crow0 + mi * 16 + e) * N_DIM + ccol0 + ni * 16]);
    }
  }
}

extern "C" void kernel_launch(void* const* d_in, const int* in_sizes, int n_in,
                              void* d_out, int out_size, void* d_ws, size_t ws_size,
                              hipStream_t stream) {
  const float* x    = (const float*)d_in[0];
  const int*   wq   = (const int*)d_in[1];
  const float* wsc  = (const float*)d_in[2];
  const float* bias = (const float*)d_in[3];
  float* out = (float*)d_out;

  const size_t xq_bytes = (size_t)M_DIM * K_DIM;        // 32 MB
  const size_t sx_bytes = (size_t)M_DIM * 4;            // 32 KB
  const size_t w8_bytes = (size_t)N_DIM * K_DIM;        // 64 MB
  if (ws_size < xq_bytes + sx_bytes + w8_bytes) return;

  char*  xq  = (char*)d_ws;
  float* sxp = (float*)((char*)d_ws + xq_bytes);
  char*  w8  = (char*)d_ws + xq_bytes + sx_bytes;

  quant_x_kernel<<<M_DIM, 256, 0, stream>>>(x, xq, sxp);
  repack_w_kernel<<<2048, 256, 0, stream>>>(wq, w8, N_DIM * K_DIM / 16);
  gemm_kernel<<<(M_DIM / 128) * (N_DIM / 128), 512, 0, stream>>>(
      xq, w8, wsc, sxp, bias, out);
}

// Round 16
// 872.291 us; speedup vs baseline: 3.4620x; 3.4620x over previous
//
#include <hip/hip_runtime.h>

#define M_DIM 8192
#define K_DIM 4096
#define N_DIM 16384
#define KT 32   // K tiles of 128 (= one weight scale block)

typedef __attribute__((ext_vector_type(4))) int i32x4;
typedef __attribute__((ext_vector_type(16))) int i32x16;
typedef __attribute__((ext_vector_type(16))) float f32x16;

__device__ __forceinline__ int pack4(int a, int b, int c, int d) {
  return (a & 255) | ((b & 255) << 8) | ((c & 255) << 16) | (d << 24);
}

// ---- pre-pass 1: x fp32 -> int8 per-row, sx[row] = rowmax/127 ------------
__global__ __launch_bounds__(256) void quant_x_kernel(const float* __restrict__ x,
    char* __restrict__ xq, float* __restrict__ sx) {
  const int row = blockIdx.x;
  const int tid = threadIdx.x;
  const float4* xr = reinterpret_cast<const float4*>(x + (size_t)row * K_DIM);
  float4 v[4];
  float m = 0.f;
#pragma unroll
  for (int j = 0; j < 4; ++j) {
    v[j] = xr[tid * 4 + j];
    m = fmaxf(m, fmaxf(fmaxf(fabsf(v[j].x), fabsf(v[j].y)),
                       fmaxf(fabsf(v[j].z), fabsf(v[j].w))));
  }
#pragma unroll
  for (int o = 32; o > 0; o >>= 1) m = fmaxf(m, __shfl_xor(m, o));
  __shared__ float wm[4];
  if ((tid & 63) == 0) wm[tid >> 6] = m;
  __syncthreads();
  m = fmaxf(fmaxf(wm[0], wm[1]), fmaxf(wm[2], wm[3]));
  const float r = (m > 0.f) ? 127.f / m : 0.f;
  i32x4 pk;
#pragma unroll
  for (int j = 0; j < 4; ++j)
    pk[j] = pack4((int)rintf(v[j].x * r), (int)rintf(v[j].y * r),
                  (int)rintf(v[j].z * r), (int)rintf(v[j].w * r));
  reinterpret_cast<i32x4*>(xq + (size_t)row * K_DIM)[tid] = pk;
  if (tid == 0) sx[row] = (m > 0.f) ? m / 127.f : 0.f;
}

// ---- pre-pass 2: w_q int32 -> int8 (exact) -------------------------------
__global__ void repack_w_kernel(const int* __restrict__ wq, char* __restrict__ w8, int n16) {
  int i = blockIdx.x * blockDim.x + threadIdx.x;
  const int stride = gridDim.x * blockDim.x;
  const int4* q = reinterpret_cast<const int4*>(wq);
  i32x4* o = reinterpret_cast<i32x4*>(w8);
  for (; i < n16; i += stride) {
    int4 a = q[4 * i], b = q[4 * i + 1], c = q[4 * i + 2], d = q[4 * i + 3];
    i32x4 r;
    r[0] = pack4(a.x, a.y, a.z, a.w);
    r[1] = pack4(b.x, b.y, b.z, b.w);
    r[2] = pack4(c.x, c.y, c.z, c.w);
    r[3] = pack4(d.x, d.y, d.z, d.w);
    o[i] = r;
  }
}

// ---- async global -> LDS, 16 B per lane ----------------------------------
__device__ __forceinline__ void gload16(const void* g, void* l) {
  __builtin_amdgcn_global_load_lds(
      (const __attribute__((address_space(1))) unsigned int*)g,
      (__attribute__((address_space(3))) unsigned int*)l, 16, 0, 0);
}

#define BAR() do { asm volatile("" ::: "memory"); \
                   __builtin_amdgcn_s_barrier();  \
                   asm volatile("" ::: "memory"); } while (0)

#define MFI32(a, b, c) __builtin_amdgcn_mfma_i32_32x32x32_i8(a, b, c, 0, 0, 0)

// ---- 128x128x128 8-wave int8 GEMM, 32x32x32 MFMA, 2 blocks/CU ------------
// C = sx[row] * (sum_kb ws[nb][kb] * (Aq . Bq^T)_kb) + bias
// r11 structure verbatim (schedule, staging, supertile, NT stores) with the
// MFMA shape swapped to 32x32x32 i8 (4404 vs 3944 TOPS ubench, same operand
// bytes, half the MFMA instruction count). Wave = 32x64 = 1x2 of 32x32.
__global__ __launch_bounds__(512, 4) void gemm_kernel(
    const char* __restrict__ Aq, const char* __restrict__ Bq,
    const float* __restrict__ ws, const float* __restrict__ sx,
    const float* __restrict__ bias, float* __restrict__ C) {
  // buf p (32K): A [128][128B] at p*32768, B [128][128B] at +16384.
  __shared__ __align__(128) char lds[65536 + 128];

  const int tid = threadIdx.x;
  const int lane = tid & 63, wid = tid >> 6;   // 8 waves
  const int wr = wid >> 1, wc = wid & 1;       // 4x2 wave grid, 32x64/wave

  // Supertile ordering: grid 8192 = 64(tm) x 128(tn) tiles.
  // Super = 16x16 tiles (A 8MB + B 8MB slice, L3-resident).
  const int bid = blockIdx.x;
  const int r = bid & 255;                 // block within super
  const int s = bid >> 8;                  // super id 0..31
  const int sm = s & 3, sn = s >> 2;       // 4 x 8 supers
  const int tm = sm * 16 + (r & 15);       // 0..63
  const int tn = sn * 16 + (r >> 4);       // 0..127

  // stage this block's scale row: ws[tn][0..32)
  if (tid < 32) *(float*)(lds + 65536 + tid * 4) = ws[tn * 32 + tid];

  // staging: per-lane pre-swizzled global source, linear LDS dest
  const int srow = tid >> 3;                         // 0..63
  const int kswz = ((tid & 7) ^ (srow & 7)) << 4;    // swizzled byte offset
  const char* aSrc = Aq + (size_t)(tm * 128 + srow) * K_DIM + kswz;
  const char* bSrc = Bq + (size_t)(tn * 128 + srow) * K_DIM + kswz;
  const int ldst = wid << 10;                        // wave-uniform

#define STAGE_A(tt, g, b) gload16(aSrc + (size_t)(g)*64*K_DIM + (size_t)(tt)*128, \
                                  lds + (b)*32768 + (g)*8192 + ldst)
#define STAGE_B(tt, g, b) gload16(bSrc + (size_t)(g)*64*K_DIM + (size_t)(tt)*128, \
                                  lds + (b)*32768 + 16384 + (g)*8192 + ldst)

  // fragment addressing (swizzled): 16B unit u stored at u^(row&7)
  // 32x32x32 A-frag: row = base + (lane&31), k-unit = 2*kstep + (lane>>5)
  const int lo3 = lane & 7, hi2 = lane >> 5;
  int uks[4];
#pragma unroll
  for (int ss = 0; ss < 4; ++ss) uks[ss] = ((2 * ss + hi2) ^ lo3) << 4;
  const int aoff = (wr * 32 + (lane & 31)) * 128;
  const int boff = 16384 + (wc * 64 + (lane & 31)) * 128;  // ni=0; ni=1 at +4096

  f32x16 accf0 = {0}, accf1 = {0};

  // ---- prologue: stage tiles 0 (buf0) and 1 (buf1): A(2)+B(2) each ------
  STAGE_A(0, 0, 0); STAGE_A(0, 1, 0); STAGE_B(0, 0, 0); STAGE_B(0, 1, 0);
  STAGE_A(1, 0, 1); STAGE_A(1, 1, 1); STAGE_B(1, 0, 1); STAGE_B(1, 1, 1);
  asm volatile("s_waitcnt vmcnt(4) lgkmcnt(0)" ::: "memory");  // tile 0 + scales in
  BAR();

  for (int t = 0; t < KT; ++t) {
    const int p = t & 1;
    const char* Ab = lds + p * 32768 + aoff;
    const char* Bb = lds + p * 32768 + boff;
    const float csc = *(const float*)(lds + 65536 + (t << 2));

    // ---- B fragments for this tile (8 ds_read_b128) ----------------------
    i32x4 fb0[4], fb1[4];
#pragma unroll
    for (int ss = 0; ss < 4; ++ss) {
      fb0[ss] = *(const i32x4*)(Bb + uks[ss]);
      fb1[ss] = *(const i32x4*)(Bb + 4096 + uks[ss]);
    }

    // ---- 4 k-steps: 1 A read + 2 MFMA each; iacc exact over K=128 --------
    i32x16 ia0, ia1;
    {
      const i32x16 z16 = {0};
      const i32x4 fa0 = *(const i32x4*)(Ab + uks[0]);
      __builtin_amdgcn_s_setprio(1);
      ia0 = MFI32(fa0, fb0[0], z16);
      ia1 = MFI32(fa0, fb1[0], z16);
      __builtin_amdgcn_s_setprio(0);
    }
#pragma unroll
    for (int ss = 1; ss < 4; ++ss) {
      const i32x4 fa = *(const i32x4*)(Ab + uks[ss]);
      __builtin_amdgcn_s_setprio(1);
      ia0 = MFI32(fa, fb0[ss], ia0);
      ia1 = MFI32(fa, fb1[ss], ia1);
      __builtin_amdgcn_s_setprio(0);
    }

    // ---- rescale into f32 accumulators (32 cvt + 32 fma) -----------------
#pragma unroll
    for (int e = 0; e < 16; ++e) {
      accf0[e] += csc * (float)ia0[e];
      accf1[e] += csc * (float)ia1[e];
    }

    // ---- tail: all waves done reading buf p -> restage it for t+2 -------
    BAR();
    if (t + 2 < KT) {
      STAGE_A(t + 2, 0, p); STAGE_A(t + 2, 1, p);
      STAGE_B(t + 2, 0, p); STAGE_B(t + 2, 1, p);
      asm volatile("s_waitcnt vmcnt(4)" ::: "memory");   // t+1 landed
    } else if (t == KT - 2) {
      asm volatile("s_waitcnt vmcnt(0)" ::: "memory");   // last tile landed
    }
    if (t + 1 < KT) BAR();
  }

  // ---- epilogue: 32x32 C/D layout col=lane&31,
  //      row=(e&3)+8*(e>>2)+4*(lane>>5); NT stores ------------------------
  const int ccol0 = tn * 128 + wc * 64 + (lane & 31);
  const int rbase = tm * 128 + wr * 32 + (hi2 << 2);
  const float bv0 = bias[ccol0];
  const float bv1 = bias[ccol0 + 32];
#pragma unroll
  for (int e = 0; e < 16; ++e) {
    const int row = rbase + (e & 3) + ((e >> 2) << 3);
    const float sxv = sx[row];
    __builtin_nontemporal_store(sxv * accf0[e] + bv0,
        &C[(size_t)row * N_DIM + ccol0]);
    __builtin_nontemporal_store(sxv * accf1[e] + bv1,
        &C[(size_t)row * N_DIM + ccol0 + 32]);
  }
}

extern "C" void kernel_launch(void* const* d_in, const int* in_sizes, int n_in,
                              void* d_out, int out_size, void* d_ws, size_t ws_size,
                              hipStream_t stream) {
  const float* x    = (const float*)d_in[0];
  const int*   wq   = (const int*)d_in[1];
  const float* wsc  = (const float*)d_in[2];
  const float* bias = (const float*)d_in[3];
  float* out = (float*)d_out;

  const size_t xq_bytes = (size_t)M_DIM * K_DIM;        // 32 MB
  const size_t sx_bytes = (size_t)M_DIM * 4;            // 32 KB
  const size_t w8_bytes = (size_t)N_DIM * K_DIM;        // 64 MB
  if (ws_size < xq_bytes + sx_bytes + w8_bytes) return;

  char*  xq  = (char*)d_ws;
  float* sxp = (float*)((char*)d_ws + xq_bytes);
  char*  w8  = (char*)d_ws + xq_bytes + sx_bytes;

  quant_x_kernel<<<M_DIM, 256, 0, stream>>>(x, xq, sxp);
  repack_w_kernel<<<2048, 256, 0, stream>>>(wq, w8, N_DIM * K_DIM / 16);
  gemm_kernel<<<(M_DIM / 128) * (N_DIM / 128), 512, 0, stream>>>(
      xq, w8, wsc, sxp, bias, out);
}

// Round 17
// 803.917 us; speedup vs baseline: 3.7564x; 1.0851x over previous
//
#include <hip/hip_runtime.h>

#define M_DIM 8192
#define K_DIM 4096
#define N_DIM 16384
#define KT 32   // K tiles of 128 (= one weight scale block)

typedef __attribute__((ext_vector_type(4))) int i32x4;
typedef __attribute__((ext_vector_type(4))) float f32x4;

__device__ __forceinline__ int pack4(int a, int b, int c, int d) {
  return (a & 255) | ((b & 255) << 8) | ((c & 255) << 16) | (d << 24);
}

// ---- pre-pass 1: x fp32 -> int8 per-row, sx[row] = rowmax/127 ------------
__global__ __launch_bounds__(256) void quant_x_kernel(const float* __restrict__ x,
    char* __restrict__ xq, float* __restrict__ sx) {
  const int row = blockIdx.x;
  const int tid = threadIdx.x;
  const float4* xr = reinterpret_cast<const float4*>(x + (size_t)row * K_DIM);
  float4 v[4];
  float m = 0.f;
#pragma unroll
  for (int j = 0; j < 4; ++j) {
    v[j] = xr[tid * 4 + j];
    m = fmaxf(m, fmaxf(fmaxf(fabsf(v[j].x), fabsf(v[j].y)),
                       fmaxf(fabsf(v[j].z), fabsf(v[j].w))));
  }
#pragma unroll
  for (int o = 32; o > 0; o >>= 1) m = fmaxf(m, __shfl_xor(m, o));
  __shared__ float wm[4];
  if ((tid & 63) == 0) wm[tid >> 6] = m;
  __syncthreads();
  m = fmaxf(fmaxf(wm[0], wm[1]), fmaxf(wm[2], wm[3]));
  const float r = (m > 0.f) ? 127.f / m : 0.f;
  i32x4 pk;
#pragma unroll
  for (int j = 0; j < 4; ++j)
    pk[j] = pack4((int)rintf(v[j].x * r), (int)rintf(v[j].y * r),
                  (int)rintf(v[j].z * r), (int)rintf(v[j].w * r));
  reinterpret_cast<i32x4*>(xq + (size_t)row * K_DIM)[tid] = pk;
  if (tid == 0) sx[row] = (m > 0.f) ? m / 127.f : 0.f;
}

// ---- pre-pass 2: w_q int32 -> int8 (exact) -------------------------------
__global__ void repack_w_kernel(const int* __restrict__ wq, char* __restrict__ w8, int n16) {
  int i = blockIdx.x * blockDim.x + threadIdx.x;
  const int stride = gridDim.x * blockDim.x;
  const int4* q = reinterpret_cast<const int4*>(wq);
  i32x4* o = reinterpret_cast<i32x4*>(w8);
  for (; i < n16; i += stride) {
    int4 a = q[4 * i], b = q[4 * i + 1], c = q[4 * i + 2], d = q[4 * i + 3];
    i32x4 r;
    r[0] = pack4(a.x, a.y, a.z, a.w);
    r[1] = pack4(b.x, b.y, b.z, b.w);
    r[2] = pack4(c.x, c.y, c.z, c.w);
    r[3] = pack4(d.x, d.y, d.z, d.w);
    o[i] = r;
  }
}

// ---- async global -> LDS, 16 B per lane ----------------------------------
__device__ __forceinline__ void gload16(const void* g, void* l) {
  __builtin_amdgcn_global_load_lds(
      (const __attribute__((address_space(1))) unsigned int*)g,
      (__attribute__((address_space(3))) unsigned int*)l, 16, 0, 0);
}

#define BAR() do { asm volatile("" ::: "memory"); \
                   __builtin_amdgcn_s_barrier();  \
                   asm volatile("" ::: "memory"); } while (0)

#define MFI(a, b, c) __builtin_amdgcn_mfma_i32_16x16x64_i8(a, b, c, 0, 0, 0)

// ---- 128x128x128 4-wave int8 GEMM, 64x64 waves, single-buf, 4 blocks/CU --
// C = sx[row] * (sum_kb ws[nb][kb] * (Aq . Bq^T)_kb) + bias
// LDS-traffic-minimal: 64x64 wave tiles give 0.5 ds_read_b128 per MFMA
// (r9's compute, zero conflicts, 88 VGPR). Occupancy recovered via
// SINGLE-buffered 33KB LDS -> 4 independent blocks/CU (16 waves/CU); the
// per-tile vmcnt(0) stall is hidden by TLP across the de-phased blocks.
__global__ __launch_bounds__(256, 4) void gemm_kernel(
    const char* __restrict__ Aq, const char* __restrict__ Bq,
    const float* __restrict__ ws, const float* __restrict__ sx,
    const float* __restrict__ bias, float* __restrict__ C) {
  // A [128][128B] at 0 (16KB), B [128][128B] at 16384, scales at 32768.
  __shared__ __align__(128) char lds[32768 + 128];

  const int tid = threadIdx.x;
  const int lane = tid & 63, wid = tid >> 6;   // 4 waves
  const int wr = wid >> 1, wc = wid & 1;       // 2x2 wave grid, 64x64/wave

  // Supertile ordering: grid 8192 = 64(tm) x 128(tn) tiles.
  // Super = 16x16 tiles (A 8MB + B 8MB slice, L3-resident).
  const int bid = blockIdx.x;
  const int r = bid & 255;                 // block within super
  const int s = bid >> 8;                  // super id 0..31
  const int sm = s & 3, sn = s >> 2;       // 4 x 8 supers
  const int tm = sm * 16 + (r & 15);       // 0..63
  const int tn = sn * 16 + (r >> 4);       // 0..127

  // stage this block's scale row: ws[tn][0..32)
  if (tid < 32) *(float*)(lds + 32768 + tid * 4) = ws[tn * 32 + tid];

  // staging: per-lane pre-swizzled global source, linear LDS dest
  // one STAGE call = 256 lanes x 16B = 4KB = 32 rows of 128B
  const int srow = tid >> 3;                         // 0..31
  const int kswz = ((tid & 7) ^ (srow & 7)) << 4;    // swizzled byte offset
  const char* aSrc = Aq + (size_t)(tm * 128 + srow) * K_DIM + kswz;
  const char* bSrc = Bq + (size_t)(tn * 128 + srow) * K_DIM + kswz;
  const int ldst = wid << 10;                        // wave-uniform

#define STAGE_A(tt, g) gload16(aSrc + (size_t)(g)*32*K_DIM + (size_t)(tt)*128, \
                               lds + (g)*4096 + ldst)
#define STAGE_B(tt, g) gload16(bSrc + (size_t)(g)*32*K_DIM + (size_t)(tt)*128, \
                               lds + 16384 + (g)*4096 + ldst)
#define STAGE_TILE(tt) do { \
    STAGE_A(tt, 0); STAGE_A(tt, 1); STAGE_A(tt, 2); STAGE_A(tt, 3); \
    STAGE_B(tt, 0); STAGE_B(tt, 1); STAGE_B(tt, 2); STAGE_B(tt, 3); \
  } while (0)

  // fragment addressing (swizzled): 16B unit u stored at u^(row&7); row&7==lane&7
  const int hi = lane >> 4, lo3 = lane & 7;
  const int aks0 = ((0 + hi) ^ lo3) << 4;   // kstep 0 (k 0..63)
  const int aks1 = ((4 + hi) ^ lo3) << 4;   // kstep 1 (k 64..127)
  const int aoff = (wr * 64 + (lane & 15)) * 128;
  const int boff = 16384 + (wc * 64 + (lane & 15)) * 128;

  f32x4 accf[4][4] = {};

  // ---- prologue: stage tile 0 ------------------------------------------
  STAGE_TILE(0);
  asm volatile("s_waitcnt vmcnt(0) lgkmcnt(0)" ::: "memory");  // tile 0 + scales in
  BAR();

  for (int t = 0; t < KT; ++t) {
    const char* Ab = lds + aoff;
    const char* Bb = lds + boff;
    const float csc = *(const float*)(lds + 32768 + (t << 2));

    // ---- B fragments (8 ds_read_b128) ------------------------------------
    i32x4 fb[4][2];
#pragma unroll
    for (int ni = 0; ni < 4; ++ni) {
      fb[ni][0] = *(const i32x4*)(Bb + ni * 2048 + aks0);
      fb[ni][1] = *(const i32x4*)(Bb + ni * 2048 + aks1);
    }

    // ---- per mi-group: 2 A reads, 8 MFMA, immediate rescale --------------
#pragma unroll
    for (int mi = 0; mi < 4; ++mi) {
      const i32x4 fa0 = *(const i32x4*)(Ab + mi * 2048 + aks0);
      const i32x4 fa1 = *(const i32x4*)(Ab + mi * 2048 + aks1);
      i32x4 q0, q1, q2, q3;
      const i32x4 z4 = {0, 0, 0, 0};
      __builtin_amdgcn_s_setprio(1);
      q0 = MFI(fa0, fb[0][0], z4);
      q1 = MFI(fa0, fb[1][0], z4);
      q2 = MFI(fa0, fb[2][0], z4);
      q3 = MFI(fa0, fb[3][0], z4);
      q0 = MFI(fa1, fb[0][1], q0);
      q1 = MFI(fa1, fb[1][1], q1);
      q2 = MFI(fa1, fb[2][1], q2);
      q3 = MFI(fa1, fb[3][1], q3);
      __builtin_amdgcn_s_setprio(0);
#pragma unroll
      for (int e = 0; e < 4; ++e) {
        accf[mi][0][e] += csc * (float)q0[e];
        accf[mi][1][e] += csc * (float)q1[e];
        accf[mi][2][e] += csc * (float)q2[e];
        accf[mi][3][e] += csc * (float)q3[e];
      }
    }

    // ---- single-buffer turnover: all reads retired (lgkm waits precede
    //      the MFMAs above), so after BAR the buffer is dead -> restage ---
    BAR();
    if (t + 1 < KT) {
      STAGE_TILE(t + 1);
      asm volatile("s_waitcnt vmcnt(0)" ::: "memory");  // tile t+1 landed
      BAR();
    }
  }

  // ---- epilogue: C/D layout col=lane&15, row=(lane>>4)*4+reg; NT stores --
  const int crow0 = tm * 128 + wr * 64 + ((lane >> 4) << 2);
  const int ccol0 = tn * 128 + wc * 64 + (lane & 15);
#pragma unroll
  for (int mi = 0; mi < 4; ++mi) {
    float sxv[4];
#pragma unroll
    for (int e = 0; e < 4; ++e) sxv[e] = sx[crow0 + mi * 16 + e];
#pragma unroll
    for (int ni = 0; ni < 4; ++ni) {
      const float bv = bias[ccol0 + ni * 16];
#pragma unroll
      for (int e = 0; e < 4; ++e)
        __builtin_nontemporal_store(
            sxv[e] * accf[mi][ni][e] + bv,
            &C[(size_t)(crow0 + mi * 16 + e) * N_DIM + ccol0 + ni * 16]);
    }
  }
}

extern "C" void kernel_launch(void* const* d_in, const int* in_sizes, int n_in,
                              void* d_out, int out_size, void* d_ws, size_t ws_size,
                              hipStream_t stream) {
  const float* x    = (const float*)d_in[0];
  const int*   wq   = (const int*)d_in[1];
  const float* wsc  = (const float*)d_in[2];
  const float* bias = (const float*)d_in[3];
  float* out = (float*)d_out;

  const size_t xq_bytes = (size_t)M_DIM * K_DIM;        // 32 MB
  const size_t sx_bytes = (size_t)M_DIM * 4;            // 32 KB
  const size_t w8_bytes = (size_t)N_DIM * K_DIM;        // 64 MB
  if (ws_size < xq_bytes + sx_bytes + w8_bytes) return;

  char*  xq  = (char*)d_ws;
  float* sxp = (float*)((char*)d_ws + xq_bytes);
  char*  w8  = (char*)d_ws + xq_bytes + sx_bytes;

  quant_x_kernel<<<M_DIM, 256, 0, stream>>>(x, xq, sxp);
  repack_w_kernel<<<2048, 256, 0, stream>>>(wq, w8, N_DIM * K_DIM / 16);
  gemm_kernel<<<(M_DIM / 128) * (N_DIM / 128), 256, 0, stream>>>(
      xq, w8, wsc, sxp, bias, out);
}

// Round 18
// 777.232 us; speedup vs baseline: 3.8854x; 1.0343x over previous
//
#include <hip/hip_runtime.h>

#define M_DIM 8192
#define K_DIM 4096
#define N_DIM 16384
#define KT 32   // K tiles of 128 (= one weight scale block)

typedef __attribute__((ext_vector_type(4))) int i32x4;
typedef __attribute__((ext_vector_type(4))) float f32x4;

__device__ __forceinline__ int pack4(int a, int b, int c, int d) {
  return (a & 255) | ((b & 255) << 8) | ((c & 255) << 16) | (d << 24);
}

// ---- pre-pass 1: x fp32 -> int8 per-row, sx[row] = rowmax/127 ------------
__global__ __launch_bounds__(256) void quant_x_kernel(const float* __restrict__ x,
    char* __restrict__ xq, float* __restrict__ sx) {
  const int row = blockIdx.x;
  const int tid = threadIdx.x;
  const float4* xr = reinterpret_cast<const float4*>(x + (size_t)row * K_DIM);
  float4 v[4];
  float m = 0.f;
#pragma unroll
  for (int j = 0; j < 4; ++j) {
    v[j] = xr[tid * 4 + j];
    m = fmaxf(m, fmaxf(fmaxf(fabsf(v[j].x), fabsf(v[j].y)),
                       fmaxf(fabsf(v[j].z), fabsf(v[j].w))));
  }
#pragma unroll
  for (int o = 32; o > 0; o >>= 1) m = fmaxf(m, __shfl_xor(m, o));
  __shared__ float wm[4];
  if ((tid & 63) == 0) wm[tid >> 6] = m;
  __syncthreads();
  m = fmaxf(fmaxf(wm[0], wm[1]), fmaxf(wm[2], wm[3]));
  const float r = (m > 0.f) ? 127.f / m : 0.f;
  i32x4 pk;
#pragma unroll
  for (int j = 0; j < 4; ++j)
    pk[j] = pack4((int)rintf(v[j].x * r), (int)rintf(v[j].y * r),
                  (int)rintf(v[j].z * r), (int)rintf(v[j].w * r));
  reinterpret_cast<i32x4*>(xq + (size_t)row * K_DIM)[tid] = pk;
  if (tid == 0) sx[row] = (m > 0.f) ? m / 127.f : 0.f;
}

// ---- pre-pass 2: w_q int32 -> int8 (exact) -------------------------------
__global__ void repack_w_kernel(const int* __restrict__ wq, char* __restrict__ w8, int n16) {
  int i = blockIdx.x * blockDim.x + threadIdx.x;
  const int stride = gridDim.x * blockDim.x;
  const int4* q = reinterpret_cast<const int4*>(wq);
  i32x4* o = reinterpret_cast<i32x4*>(w8);
  for (; i < n16; i += stride) {
    int4 a = q[4 * i], b = q[4 * i + 1], c = q[4 * i + 2], d = q[4 * i + 3];
    i32x4 r;
    r[0] = pack4(a.x, a.y, a.z, a.w);
    r[1] = pack4(b.x, b.y, b.z, b.w);
    r[2] = pack4(c.x, c.y, c.z, c.w);
    r[3] = pack4(d.x, d.y, d.z, d.w);
    o[i] = r;
  }
}

// ---- async global -> LDS, 16 B per lane ----------------------------------
__device__ __forceinline__ void gload16(const void* g, void* l) {
  __builtin_amdgcn_global_load_lds(
      (const __attribute__((address_space(1))) unsigned int*)g,
      (__attribute__((address_space(3))) unsigned int*)l, 16, 0, 0);
}

#define BAR() do { asm volatile("" ::: "memory"); \
                   __builtin_amdgcn_s_barrier();  \
                   asm volatile("" ::: "memory"); } while (0)

#define MFI(a, b, c) __builtin_amdgcn_mfma_i32_16x16x64_i8(a, b, c, 0, 0, 0)

// ---- 128x128x128 4-wave int8 GEMM, 64x64 waves, single-buf ---------------
// C = sx[row] * (sum_kb ws[nb][kb] * (Aq . Bq^T)_kb) + bias
// r17 structure verbatim; launch_bounds relaxed (256,4)->(256,2) so the
// allocator uses ~88 VGPR (r9-proven, no spill) instead of force-fitting
// 128 and spilling accf. 88x4 waves/SIMD = 352 <= 512 regs and 4x33KB
// LDS <= 160KB, so 4 blocks/CU still co-reside.
__global__ __launch_bounds__(256, 2) void gemm_kernel(
    const char* __restrict__ Aq, const char* __restrict__ Bq,
    const float* __restrict__ ws, const float* __restrict__ sx,
    const float* __restrict__ bias, float* __restrict__ C) {
  // A [128][128B] at 0 (16KB), B [128][128B] at 16384, scales at 32768.
  __shared__ __align__(128) char lds[32768 + 128];

  const int tid = threadIdx.x;
  const int lane = tid & 63, wid = tid >> 6;   // 4 waves
  const int wr = wid >> 1, wc = wid & 1;       // 2x2 wave grid, 64x64/wave

  // Supertile ordering: grid 8192 = 64(tm) x 128(tn) tiles.
  // Super = 16x16 tiles (A 8MB + B 8MB slice, L3-resident).
  const int bid = blockIdx.x;
  const int r = bid & 255;                 // block within super
  const int s = bid >> 8;                  // super id 0..31
  const int sm = s & 3, sn = s >> 2;       // 4 x 8 supers
  const int tm = sm * 16 + (r & 15);       // 0..63
  const int tn = sn * 16 + (r >> 4);       // 0..127

  // stage this block's scale row: ws[tn][0..32)
  if (tid < 32) *(float*)(lds + 32768 + tid * 4) = ws[tn * 32 + tid];

  // staging: per-lane pre-swizzled global source, linear LDS dest
  // one STAGE call = 256 lanes x 16B = 4KB = 32 rows of 128B
  const int srow = tid >> 3;                         // 0..31
  const int kswz = ((tid & 7) ^ (srow & 7)) << 4;    // swizzled byte offset
  const char* aSrc = Aq + (size_t)(tm * 128 + srow) * K_DIM + kswz;
  const char* bSrc = Bq + (size_t)(tn * 128 + srow) * K_DIM + kswz;
  const int ldst = wid << 10;                        // wave-uniform

#define STAGE_A(tt, g) gload16(aSrc + (size_t)(g)*32*K_DIM + (size_t)(tt)*128, \
                               lds + (g)*4096 + ldst)
#define STAGE_B(tt, g) gload16(bSrc + (size_t)(g)*32*K_DIM + (size_t)(tt)*128, \
                               lds + 16384 + (g)*4096 + ldst)
#define STAGE_TILE(tt) do { \
    STAGE_A(tt, 0); STAGE_A(tt, 1); STAGE_A(tt, 2); STAGE_A(tt, 3); \
    STAGE_B(tt, 0); STAGE_B(tt, 1); STAGE_B(tt, 2); STAGE_B(tt, 3); \
  } while (0)

  // fragment addressing (swizzled): 16B unit u stored at u^(row&7); row&7==lane&7
  const int hi = lane >> 4, lo3 = lane & 7;
  const int aks0 = ((0 + hi) ^ lo3) << 4;   // kstep 0 (k 0..63)
  const int aks1 = ((4 + hi) ^ lo3) << 4;   // kstep 1 (k 64..127)
  const int aoff = (wr * 64 + (lane & 15)) * 128;
  const int boff = 16384 + (wc * 64 + (lane & 15)) * 128;

  f32x4 accf[4][4] = {};

  // ---- prologue: stage tile 0 ------------------------------------------
  STAGE_TILE(0);
  asm volatile("s_waitcnt vmcnt(0) lgkmcnt(0)" ::: "memory");  // tile 0 + scales in
  BAR();

  for (int t = 0; t < KT; ++t) {
    const char* Ab = lds + aoff;
    const char* Bb = lds + boff;
    const float csc = *(const float*)(lds + 32768 + (t << 2));

    // ---- B fragments (8 ds_read_b128) ------------------------------------
    i32x4 fb[4][2];
#pragma unroll
    for (int ni = 0; ni < 4; ++ni) {
      fb[ni][0] = *(const i32x4*)(Bb + ni * 2048 + aks0);
      fb[ni][1] = *(const i32x4*)(Bb + ni * 2048 + aks1);
    }

    // ---- per mi-group: 2 A reads, 8 MFMA, immediate rescale --------------
#pragma unroll
    for (int mi = 0; mi < 4; ++mi) {
      const i32x4 fa0 = *(const i32x4*)(Ab + mi * 2048 + aks0);
      const i32x4 fa1 = *(const i32x4*)(Ab + mi * 2048 + aks1);
      i32x4 q0, q1, q2, q3;
      const i32x4 z4 = {0, 0, 0, 0};
      __builtin_amdgcn_s_setprio(1);
      q0 = MFI(fa0, fb[0][0], z4);
      q1 = MFI(fa0, fb[1][0], z4);
      q2 = MFI(fa0, fb[2][0], z4);
      q3 = MFI(fa0, fb[3][0], z4);
      q0 = MFI(fa1, fb[0][1], q0);
      q1 = MFI(fa1, fb[1][1], q1);
      q2 = MFI(fa1, fb[2][1], q2);
      q3 = MFI(fa1, fb[3][1], q3);
      __builtin_amdgcn_s_setprio(0);
#pragma unroll
      for (int e = 0; e < 4; ++e) {
        accf[mi][0][e] += csc * (float)q0[e];
        accf[mi][1][e] += csc * (float)q1[e];
        accf[mi][2][e] += csc * (float)q2[e];
        accf[mi][3][e] += csc * (float)q3[e];
      }
    }

    // ---- single-buffer turnover: all reads retired (lgkm waits precede
    //      the MFMAs above), so after BAR the buffer is dead -> restage ---
    BAR();
    if (t + 1 < KT) {
      STAGE_TILE(t + 1);
      asm volatile("s_waitcnt vmcnt(0)" ::: "memory");  // tile t+1 landed
      BAR();
    }
  }

  // ---- epilogue: C/D layout col=lane&15, row=(lane>>4)*4+reg; NT stores --
  const int crow0 = tm * 128 + wr * 64 + ((lane >> 4) << 2);
  const int ccol0 = tn * 128 + wc * 64 + (lane & 15);
#pragma unroll
  for (int mi = 0; mi < 4; ++mi) {
    float sxv[4];
#pragma unroll
    for (int e = 0; e < 4; ++e) sxv[e] = sx[crow0 + mi * 16 + e];
#pragma unroll
    for (int ni = 0; ni < 4; ++ni) {
      const float bv = bias[ccol0 + ni * 16];
#pragma unroll
      for (int e = 0; e < 4; ++e)
        __builtin_nontemporal_store(
            sxv[e] * accf[mi][ni][e] + bv,
            &C[(size_t)(crow0 + mi * 16 + e) * N_DIM + ccol0 + ni * 16]);
    }
  }
}

extern "C" void kernel_launch(void* const* d_in, const int* in_sizes, int n_in,
                              void* d_out, int out_size, void* d_ws, size_t ws_size,
                              hipStream_t stream) {
  const float* x    = (const float*)d_in[0];
  const int*   wq   = (const int*)d_in[1];
  const float* wsc  = (const float*)d_in[2];
  const float* bias = (const float*)d_in[3];
  float* out = (float*)d_out;

  const size_t xq_bytes = (size_t)M_DIM * K_DIM;        // 32 MB
  const size_t sx_bytes = (size_t)M_DIM * 4;            // 32 KB
  const size_t w8_bytes = (size_t)N_DIM * K_DIM;        // 64 MB
  if (ws_size < xq_bytes + sx_bytes + w8_bytes) return;

  char*  xq  = (char*)d_ws;
  float* sxp = (float*)((char*)d_ws + xq_bytes);
  char*  w8  = (char*)d_ws + xq_bytes + sx_bytes;

  quant_x_kernel<<<M_DIM, 256, 0, stream>>>(x, xq, sxp);
  repack_w_kernel<<<2048, 256, 0, stream>>>(wq, w8, N_DIM * K_DIM / 16);
  gemm_kernel<<<(M_DIM / 128) * (N_DIM / 128), 256, 0, stream>>>(
      xq, w8, wsc, sxp, bias, out);
}